// Round 10
// baseline (43.752 us; speedup 1.0000x reference)
//
#include <hip/hip_runtime.h>

static constexpr int NB = 4;    // batch
static constexpr int L  = 256;  // Lx == Lm
static constexpr int D  = 256;

__device__ __forceinline__ float fast_rcp(float x) {
#if __has_builtin(__builtin_amdgcn_rcpf)
    return __builtin_amdgcn_rcpf(x);
#else
    return 1.0f / x;
#endif
}

__device__ __forceinline__ float fast_exp(float x) {   // e^x
#if __has_builtin(__builtin_amdgcn_exp2f)
    return __builtin_amdgcn_exp2f(x * 1.4426950408889634f);
#else
    return __expf(x);
#endif
}

__device__ __forceinline__ float exp_2x(float x) {     // e^(2x)
#if __has_builtin(__builtin_amdgcn_exp2f)
    return __builtin_amdgcn_exp2f(x * 2.8853900817779268f);
#else
    return __expf(2.0f * x);
#endif
}

// ---------------------------------------------------------------------------
// K1 (LDS-free): E = exp(2*(src@W^T+b)), row-major.
// 512 blocks = 32 rowgroups(64 rows) x 16 colgroups(16 cols).
// lane = row in strip (x loads per-lane coalesced, strip shared by all 4
// waves -> L1-hot); wave owns 4 cols, W rows via readfirstlane -> s_load.
// Rowgroups 0..15 -> E1 (x,W1,b1); 16..31 -> E2 (mem,W2).
// ---------------------------------------------------------------------------
__global__ __launch_bounds__(256) void linear_kernel(
    const float* __restrict__ x, const float* __restrict__ mem,
    const float* __restrict__ w1, const float* __restrict__ b1,
    const float* __restrict__ w2,
    float* __restrict__ E1R, float* __restrict__ E2R)
{
    const int bid = blockIdx.x;          // rg*16 + cg (consecutive = same strip)
    const int rg  = bid >> 4;            // 0..31
    const int cg  = bid & 15;            // 0..15
    const int rbase = rg * 64;           // 0..2047
    const int which = rbase >= 1024;
    const int rloc  = which ? rbase - 1024 : rbase;   // == b*L + row0
    const float* src = which ? mem : x;
    const float* W   = which ? w2  : w1;
    float*       dst = which ? E2R : E1R;

    const int t    = threadIdx.x;
    const int wv   = t >> 6;             // wave 0..3
    const int lane = t & 63;             // row within strip
    const int row  = rloc + lane;

    const int c0u = __builtin_amdgcn_readfirstlane(cg * 16 + wv * 4);

    const float4* x4 = reinterpret_cast<const float4*>(src) + row * 64;
    const float4* Wp = reinterpret_cast<const float4*>(W) + c0u * 64;

    float acc0 = 0.f, acc1 = 0.f, acc2 = 0.f, acc3 = 0.f;
#pragma unroll 4
    for (int d4 = 0; d4 < 64; ++d4) {
        float4 xv = x4[d4];                       // per-lane coalesced
        float4 wA = Wp[d4];                       // uniform -> s_load_dwordx4
        float4 wB = Wp[64  + d4];
        float4 wC = Wp[128 + d4];
        float4 wD = Wp[192 + d4];
        acc0 = fmaf(xv.x, wA.x, acc0); acc0 = fmaf(xv.y, wA.y, acc0);
        acc0 = fmaf(xv.z, wA.z, acc0); acc0 = fmaf(xv.w, wA.w, acc0);
        acc1 = fmaf(xv.x, wB.x, acc1); acc1 = fmaf(xv.y, wB.y, acc1);
        acc1 = fmaf(xv.z, wB.z, acc1); acc1 = fmaf(xv.w, wB.w, acc1);
        acc2 = fmaf(xv.x, wC.x, acc2); acc2 = fmaf(xv.y, wC.y, acc2);
        acc2 = fmaf(xv.z, wC.z, acc2); acc2 = fmaf(xv.w, wC.w, acc2);
        acc3 = fmaf(xv.x, wD.x, acc3); acc3 = fmaf(xv.y, wD.y, acc3);
        acc3 = fmaf(xv.z, wD.z, acc3); acc3 = fmaf(xv.w, wD.w, acc3);
    }
    float bias0 = 0.f, bias1 = 0.f, bias2 = 0.f, bias3 = 0.f;
    if (!which) {
        bias0 = b1[c0u];     bias1 = b1[c0u + 1];
        bias2 = b1[c0u + 2]; bias3 = b1[c0u + 3];
    }
    float* drow = dst + row * D + c0u;
    drow[0] = exp_2x(acc0 + bias0);
    drow[1] = exp_2x(acc1 + bias1);
    drow[2] = exp_2x(acc2 + bias2);
    drow[3] = exp_2x(acc3 + bias3);
}

// ---------------------------------------------------------------------------
// K2: score. 16x x 32m tile, 1x2 micro-tile. term: w*rcp(fma(e1,e2,1));
// S = W_tot - 2*acc.  Writes masked Smask + raw S^T.
// XCD swizzle: bid&7 -> (batch, xg-half) so each batch's E is L2-local.
// ---------------------------------------------------------------------------
__global__ __launch_bounds__(256) void score_kernel(
    const float* __restrict__ E1R, const float* __restrict__ E2R,
    const float* __restrict__ wst, const int* __restrict__ mask,
    float* __restrict__ Smask, float* __restrict__ ST)
{
    const int bid = blockIdx.x;           // 512
    const int p   = bid & 7, q = bid >> 3;
    const int b   = p >> 1;
    const int xg  = (q & 7) | ((p & 1) << 3);   // 0..15
    const int mg  = q >> 3;                     // 0..7
    const int xt  = xg * 16, mt = mg * 32;
    const int base = b * L;
    const int t   = threadIdx.x;

    constexpr int P4 = 65;
    __shared__ __align__(16) float4 s1[16 * P4];
    __shared__ __align__(16) float4 s2[32 * P4];
    __shared__ float stile[32 * 17];

    const float4* e14 = reinterpret_cast<const float4*>(E1R) + (base + xt) * 64;
    const float4* e24 = reinterpret_cast<const float4*>(E2R) + (base + mt) * 64;
#pragma unroll
    for (int k = 0; k < 4; ++k) {
        int idx = k * 256 + t;
        int r = idx >> 6, c = idx & 63;
        s1[r * P4 + c] = e14[r * 64 + c];
    }
#pragma unroll
    for (int k = 0; k < 8; ++k) {
        int idx = k * 256 + t;
        int r = idx >> 6, c = idx & 63;
        s2[r * P4 + c] = e24[r * 64 + c];
    }
    __syncthreads();

    const float4* w4 = reinterpret_cast<const float4*>(wst);
    float W_tot;
    {   // sum(wst) via lane-parallel read + shuffle reduce
        float4 wv = w4[t & 63];
        float s = (wv.x + wv.y) + (wv.z + wv.w);
#pragma unroll
        for (int o = 32; o; o >>= 1) s += __shfl_xor(s, o);
        W_tot = s;
    }

    const int rr = t >> 4, cc = t & 15;   // x-row rr; m-cols {cc, cc+16}
    const float4* ap  = s1 + rr * P4;
    const float4* b0p = s2 + cc * P4;
    const float4* b1p = s2 + (cc + 16) * P4;
    float acc0 = 0.f, acc1 = 0.f;
#pragma unroll 4
    for (int d4 = 0; d4 < 64; ++d4) {
        float4 a  = ap[d4];
        float4 b0 = b0p[d4], b1 = b1p[d4];
        float4 wv = w4[d4];               // uniform -> s_load
        acc0 = fmaf(wv.x, fast_rcp(fmaf(a.x, b0.x, 1.f)), acc0);
        acc0 = fmaf(wv.y, fast_rcp(fmaf(a.y, b0.y, 1.f)), acc0);
        acc0 = fmaf(wv.z, fast_rcp(fmaf(a.z, b0.z, 1.f)), acc0);
        acc0 = fmaf(wv.w, fast_rcp(fmaf(a.w, b0.w, 1.f)), acc0);
        acc1 = fmaf(wv.x, fast_rcp(fmaf(a.x, b1.x, 1.f)), acc1);
        acc1 = fmaf(wv.y, fast_rcp(fmaf(a.y, b1.y, 1.f)), acc1);
        acc1 = fmaf(wv.z, fast_rcp(fmaf(a.z, b1.z, 1.f)), acc1);
        acc1 = fmaf(wv.w, fast_rcp(fmaf(a.w, b1.w, 1.f)), acc1);
    }
    const float S0 = fmaf(-2.f, acc0, W_tot);
    const float S1 = fmaf(-2.f, acc1, W_tot);

    const int m0 = mt + cc, m1 = mt + cc + 16, x0 = xt + rr;
    Smask[((base + x0) << 8) + m0] = (mask[base + m0] == 0) ? -1e30f : S0;
    Smask[((base + x0) << 8) + m1] = (mask[base + m1] == 0) ? -1e30f : S1;

    stile[cc        * 17 + rr] = S0;      // raw S^T tile
    stile[(cc + 16) * 17 + rr] = S1;
    __syncthreads();
#pragma unroll
    for (int k = 0; k < 2; ++k) {
        int idx = k * 256 + t;
        int mr = idx >> 4, xc = idx & 15;
        ST[((base + mt + mr) << 8) + xt + xc] = stile[mr * 17 + xc];
    }
}

// ---------------------------------------------------------------------------
// K3: both attentions, 8 rows/block, 256 blocks.
// XCD swizzle: bid&7 -> (side, batch): all 32 blocks sharing one 256 KB V
// panel land on one XCD -> V stays L2-local.
// Max-free softmax (|S|<=~10; masked -1e30 -> exp=0); normalize at store.
// ---------------------------------------------------------------------------
__global__ __launch_bounds__(256) void attn_kernel(
    const float* __restrict__ x, const float* __restrict__ mem,
    const float* __restrict__ Smask, const float* __restrict__ ST,
    float* __restrict__ out, float* __restrict__ agg)
{
    const int bid  = blockIdx.x;          // 256
    const int p    = bid & 7, g = bid >> 3;
    const int side = p & 1,  b = p >> 1;
    const float* S = side ? ST : Smask;
    const float* V = side ? x  : mem;
    float*       o = side ? agg : out;
    const int base = b * L;
    const int row0 = g * 8;
    const int t = threadIdx.x, w = t >> 6, l = t & 63;

    __shared__ __align__(16) float  ps[8][L];        // exp(S), unnormalized
    __shared__ __align__(16) float4 part[8][4][64];  // PV partials

    // exp pass: wave w owns rows {w, w+4}; keep row-sum reciprocals in regs
    float rs0, rs1;
#pragma unroll
    for (int rr = w, it = 0; rr < 8; rr += 4, ++it) {
        float4 sv = reinterpret_cast<const float4*>(S)[((base + row0 + rr) << 6) + l];
        float e0 = fast_exp(sv.x), e1 = fast_exp(sv.y);
        float e2 = fast_exp(sv.z), e3 = fast_exp(sv.w);
        reinterpret_cast<float4*>(ps[rr])[l] = make_float4(e0, e1, e2, e3);
        float s = (e0 + e1) + (e2 + e3);
#pragma unroll
        for (int off = 32; off; off >>= 1) s += __shfl_xor(s, off);
        if (it == 0) rs0 = fast_rcp(s); else rs1 = fast_rcp(s);
    }
    __syncthreads();

    // P @ V: wave w covers k in [64w,64w+64), lane l owns d4=l
    const float4* V4 = reinterpret_cast<const float4*>(V) + base * 64;
    float4 acc[8];
#pragma unroll
    for (int r = 0; r < 8; ++r) acc[r] = make_float4(0.f, 0.f, 0.f, 0.f);

#pragma unroll 2
    for (int k4 = 0; k4 < 16; ++k4) {
        const int m0 = w * 64 + k4 * 4;
        float4 v0 = V4[(m0 + 0) * 64 + l];
        float4 v1 = V4[(m0 + 1) * 64 + l];
        float4 v2 = V4[(m0 + 2) * 64 + l];
        float4 v3 = V4[(m0 + 3) * 64 + l];
#pragma unroll
        for (int r = 0; r < 8; ++r) {
            float4 pr = *reinterpret_cast<const float4*>(&ps[r][m0]);  // uniform b128
            acc[r].x = fmaf(pr.x, v0.x, acc[r].x); acc[r].y = fmaf(pr.x, v0.y, acc[r].y);
            acc[r].z = fmaf(pr.x, v0.z, acc[r].z); acc[r].w = fmaf(pr.x, v0.w, acc[r].w);
            acc[r].x = fmaf(pr.y, v1.x, acc[r].x); acc[r].y = fmaf(pr.y, v1.y, acc[r].y);
            acc[r].z = fmaf(pr.y, v1.z, acc[r].z); acc[r].w = fmaf(pr.y, v1.w, acc[r].w);
            acc[r].x = fmaf(pr.z, v2.x, acc[r].x); acc[r].y = fmaf(pr.z, v2.y, acc[r].y);
            acc[r].z = fmaf(pr.z, v2.z, acc[r].z); acc[r].w = fmaf(pr.z, v2.w, acc[r].w);
            acc[r].x = fmaf(pr.w, v3.x, acc[r].x); acc[r].y = fmaf(pr.w, v3.y, acc[r].y);
            acc[r].z = fmaf(pr.w, v3.z, acc[r].z); acc[r].w = fmaf(pr.w, v3.w, acc[r].w);
        }
    }
#pragma unroll
    for (int r = 0; r < 8; ++r) part[r][w][l] = acc[r];
    __syncthreads();

    // reduce: wave w handles rows {w, w+4}, normalize, store
#pragma unroll
    for (int rr = w, it = 0; rr < 8; rr += 4, ++it) {
        float rs = (it == 0) ? rs0 : rs1;
        float4 q0 = part[rr][0][l], q1 = part[rr][1][l];
        float4 q2 = part[rr][2][l], q3 = part[rr][3][l];
        float4 ov;
        ov.x = ((q0.x + q1.x) + (q2.x + q3.x)) * rs;
        ov.y = ((q0.y + q1.y) + (q2.y + q3.y)) * rs;
        ov.z = ((q0.z + q1.z) + (q2.z + q3.z)) * rs;
        ov.w = ((q0.w + q1.w) + (q2.w + q3.w)) * rs;
        reinterpret_cast<float4*>(o)[((base + row0 + rr) << 6) + l] = ov;
    }
}

extern "C" void kernel_launch(void* const* d_in, const int* in_sizes, int n_in,
                              void* d_out, int out_size, void* d_ws, size_t ws_size,
                              hipStream_t stream)
{
    const float* x    = (const float*)d_in[0];  // [4,256,256]
    const float* mem  = (const float*)d_in[1];  // [4,256,256]
    const int*   mask = (const int*)  d_in[2];  // [4,256]
    const float* w1   = (const float*)d_in[3];  // [256,256]
    const float* b1   = (const float*)d_in[4];  // [256]
    const float* w2   = (const float*)d_in[5];  // [256,256]
    const float* wst  = (const float*)d_in[6];  // [256]

    float* out   = (float*)d_out;               // [4,256,256]
    float* Smask = out + NB * L * L;            // [4,256,256] (masked S, output 1)
    float* agg   = Smask + NB * L * L;          // [4,256,256] (agg_2_h, output 2)

    float* E1R = (float*)d_ws;                  // 1 MiB each
    float* E2R = E1R + NB * L * D;
    float* ST  = E2R + NB * L * D;              // raw S^T

    linear_kernel<<<512, 256, 0, stream>>>(x, mem, w1, b1, w2, E1R, E2R);
    score_kernel<<<512, 256, 0, stream>>>(E1R, E2R, wst, mask, Smask, ST);
    attn_kernel<<<256, 256, 0, stream>>>(x, mem, Smask, ST, out, agg);
}

// Round 11
// 35.342 us; speedup vs baseline: 1.2379x; 1.2379x over previous
//
#include <hip/hip_runtime.h>

static constexpr int NB = 4;    // batch
static constexpr int L  = 256;  // Lx == Lm
static constexpr int D  = 256;

__device__ __forceinline__ float fast_rcp(float x) {
#if __has_builtin(__builtin_amdgcn_rcpf)
    return __builtin_amdgcn_rcpf(x);
#else
    return 1.0f / x;
#endif
}

__device__ __forceinline__ float fast_exp(float x) {   // e^x
#if __has_builtin(__builtin_amdgcn_exp2f)
    return __builtin_amdgcn_exp2f(x * 1.4426950408889634f);
#else
    return __expf(x);
#endif
}

__device__ __forceinline__ float exp_2x(float x) {     // e^(2x)
#if __has_builtin(__builtin_amdgcn_exp2f)
    return __builtin_amdgcn_exp2f(x * 2.8853900817779268f);
#else
    return __expf(2.0f * x);
#endif
}

// ---------------------------------------------------------------------------
// K1: tiled GEMM for both linears; writes E = exp(2*(src@W^T+b)), row-major.
// Row space 0..1023 -> E1 (x,W1,b1); 1024..2047 -> E2 (mem,W2).
// Block = 32x32 tile, thread = 2x2 micro-tile. LDS rows padded (P4=65).
// ---------------------------------------------------------------------------
__global__ __launch_bounds__(256) void linear_kernel(
    const float* __restrict__ x, const float* __restrict__ mem,
    const float* __restrict__ w1, const float* __restrict__ b1,
    const float* __restrict__ w2,
    float* __restrict__ E1R, float* __restrict__ E2R)
{
    const int bid = blockIdx.x;           // 512: 64 rowgroups x 8 colgroups
    const int rb  = (bid >> 3) * 32;      // 0..2047
    const int cb  = (bid & 7) * 32;
    const int which = rb >= 1024;
    const int rloc  = which ? rb - 1024 : rb;   // == b*L + row
    const float* src = which ? mem : x;
    const float* W   = which ? w2  : w1;
    float*      dstR = which ? E2R : E1R;

    constexpr int P4 = 65;
    __shared__ __align__(16) float4 xs4[32 * P4];
    __shared__ __align__(16) float4 ws4[32 * P4];

    const int t = threadIdx.x;
    const float4* src4 = reinterpret_cast<const float4*>(src) + rloc * 64;
    const float4* Wg4  = reinterpret_cast<const float4*>(W)   + cb   * 64;
#pragma unroll
    for (int k = 0; k < 8; ++k) {
        int idx = k * 256 + t;
        int r = idx >> 6, c = idx & 63;
        xs4[r * P4 + c] = src4[r * 64 + c];
        ws4[r * P4 + c] = Wg4[r * 64 + c];
    }
    __syncthreads();

    const int rr = t >> 4, cc = t & 15;   // rows {rr, rr+16}, cols {cc, cc+16}
    const float4* a0p = xs4 + rr * P4;
    const float4* a1p = xs4 + (rr + 16) * P4;
    const float4* w0p = ws4 + cc * P4;
    const float4* w1p = ws4 + (cc + 16) * P4;
    float acc00 = 0.f, acc01 = 0.f, acc10 = 0.f, acc11 = 0.f;
#pragma unroll 4
    for (int d4 = 0; d4 < 64; ++d4) {
        float4 a0 = a0p[d4], a1 = a1p[d4];
        float4 w0 = w0p[d4], w1 = w1p[d4];
        acc00 = fmaf(a0.x, w0.x, acc00); acc00 = fmaf(a0.y, w0.y, acc00);
        acc00 = fmaf(a0.z, w0.z, acc00); acc00 = fmaf(a0.w, w0.w, acc00);
        acc01 = fmaf(a0.x, w1.x, acc01); acc01 = fmaf(a0.y, w1.y, acc01);
        acc01 = fmaf(a0.z, w1.z, acc01); acc01 = fmaf(a0.w, w1.w, acc01);
        acc10 = fmaf(a1.x, w0.x, acc10); acc10 = fmaf(a1.y, w0.y, acc10);
        acc10 = fmaf(a1.z, w0.z, acc10); acc10 = fmaf(a1.w, w0.w, acc10);
        acc11 = fmaf(a1.x, w1.x, acc11); acc11 = fmaf(a1.y, w1.y, acc11);
        acc11 = fmaf(a1.z, w1.z, acc11); acc11 = fmaf(a1.w, w1.w, acc11);
    }
    const float bias0 = which ? 0.f : b1[cb + cc];
    const float bias1 = which ? 0.f : b1[cb + cc + 16];
    const int c0 = cb + cc, c1 = cb + cc + 16;
    const int rA = rloc + rr, rB = rloc + rr + 16;
    dstR[rA * D + c0] = exp_2x(acc00 + bias0);
    dstR[rA * D + c1] = exp_2x(acc01 + bias1);
    dstR[rB * D + c0] = exp_2x(acc10 + bias0);
    dstR[rB * D + c1] = exp_2x(acc11 + bias1);
}

// ---------------------------------------------------------------------------
// K2: score. 16x x 32m tile, 1x2 micro-tile. term: w*rcp(fma(e1,e2,1));
// S = W_tot - 2*acc.  Writes masked Smask + raw S^T.
// XCD swizzle: bid&7 -> (batch, xg-half) so each batch's E is L2-local.
// ---------------------------------------------------------------------------
__global__ __launch_bounds__(256) void score_kernel(
    const float* __restrict__ E1R, const float* __restrict__ E2R,
    const float* __restrict__ wst, const int* __restrict__ mask,
    float* __restrict__ Smask, float* __restrict__ ST)
{
    const int bid = blockIdx.x;           // 512
    const int p   = bid & 7, q = bid >> 3;
    const int b   = p >> 1;
    const int xg  = (q & 7) | ((p & 1) << 3);   // 0..15
    const int mg  = q >> 3;                     // 0..7
    const int xt  = xg * 16, mt = mg * 32;
    const int base = b * L;
    const int t   = threadIdx.x;

    constexpr int P4 = 65;
    __shared__ __align__(16) float4 s1[16 * P4];
    __shared__ __align__(16) float4 s2[32 * P4];
    __shared__ float stile[32 * 17];

    const float4* e14 = reinterpret_cast<const float4*>(E1R) + (base + xt) * 64;
    const float4* e24 = reinterpret_cast<const float4*>(E2R) + (base + mt) * 64;
#pragma unroll
    for (int k = 0; k < 4; ++k) {
        int idx = k * 256 + t;
        int r = idx >> 6, c = idx & 63;
        s1[r * P4 + c] = e14[r * 64 + c];
    }
#pragma unroll
    for (int k = 0; k < 8; ++k) {
        int idx = k * 256 + t;
        int r = idx >> 6, c = idx & 63;
        s2[r * P4 + c] = e24[r * 64 + c];
    }
    __syncthreads();

    const float4* w4 = reinterpret_cast<const float4*>(wst);
    float W_tot;
    {   // sum(wst) via lane-parallel read + shuffle reduce
        float4 wv = w4[t & 63];
        float s = (wv.x + wv.y) + (wv.z + wv.w);
#pragma unroll
        for (int o = 32; o; o >>= 1) s += __shfl_xor(s, o);
        W_tot = s;
    }

    const int rr = t >> 4, cc = t & 15;   // x-row rr; m-cols {cc, cc+16}
    const float4* ap  = s1 + rr * P4;
    const float4* b0p = s2 + cc * P4;
    const float4* b1p = s2 + (cc + 16) * P4;
    float acc0 = 0.f, acc1 = 0.f;
#pragma unroll 4
    for (int d4 = 0; d4 < 64; ++d4) {
        float4 a  = ap[d4];
        float4 b0 = b0p[d4], b1 = b1p[d4];
        float4 wv = w4[d4];               // uniform -> s_load
        acc0 = fmaf(wv.x, fast_rcp(fmaf(a.x, b0.x, 1.f)), acc0);
        acc0 = fmaf(wv.y, fast_rcp(fmaf(a.y, b0.y, 1.f)), acc0);
        acc0 = fmaf(wv.z, fast_rcp(fmaf(a.z, b0.z, 1.f)), acc0);
        acc0 = fmaf(wv.w, fast_rcp(fmaf(a.w, b0.w, 1.f)), acc0);
        acc1 = fmaf(wv.x, fast_rcp(fmaf(a.x, b1.x, 1.f)), acc1);
        acc1 = fmaf(wv.y, fast_rcp(fmaf(a.y, b1.y, 1.f)), acc1);
        acc1 = fmaf(wv.z, fast_rcp(fmaf(a.z, b1.z, 1.f)), acc1);
        acc1 = fmaf(wv.w, fast_rcp(fmaf(a.w, b1.w, 1.f)), acc1);
    }
    const float S0 = fmaf(-2.f, acc0, W_tot);
    const float S1 = fmaf(-2.f, acc1, W_tot);

    const int m0 = mt + cc, m1 = mt + cc + 16, x0 = xt + rr;
    Smask[((base + x0) << 8) + m0] = (mask[base + m0] == 0) ? -1e30f : S0;
    Smask[((base + x0) << 8) + m1] = (mask[base + m1] == 0) ? -1e30f : S1;

    stile[cc        * 17 + rr] = S0;      // raw S^T tile
    stile[(cc + 16) * 17 + rr] = S1;
    __syncthreads();
#pragma unroll
    for (int k = 0; k < 2; ++k) {
        int idx = k * 256 + t;
        int mr = idx >> 4, xc = idx & 15;
        ST[((base + mt + mr) << 8) + xt + xc] = stile[mr * 17 + xc];
    }
}

// ---------------------------------------------------------------------------
// K3: both attentions, 8 rows/block, 256 blocks.
// XCD swizzle: bid&7 -> (side, batch): all 32 blocks sharing one 256 KB V
// panel land on one XCD -> V stays L2-local.
// Max-free softmax (|S|<=~10; masked -1e30 -> exp=0); normalize at store.
// ---------------------------------------------------------------------------
__global__ __launch_bounds__(256) void attn_kernel(
    const float* __restrict__ x, const float* __restrict__ mem,
    const float* __restrict__ Smask, const float* __restrict__ ST,
    float* __restrict__ out, float* __restrict__ agg)
{
    const int bid  = blockIdx.x;          // 256
    const int p    = bid & 7, g = bid >> 3;
    const int side = p & 1,  b = p >> 1;
    const float* S = side ? ST : Smask;
    const float* V = side ? x  : mem;
    float*       o = side ? agg : out;
    const int base = b * L;
    const int row0 = g * 8;
    const int t = threadIdx.x, w = t >> 6, l = t & 63;

    __shared__ __align__(16) float  ps[8][L];        // exp(S), unnormalized
    __shared__ __align__(16) float4 part[8][4][64];  // PV partials

    // exp pass: wave w owns rows {w, w+4}; keep row-sum reciprocals in regs
    float rs0, rs1;
#pragma unroll
    for (int rr = w, it = 0; rr < 8; rr += 4, ++it) {
        float4 sv = reinterpret_cast<const float4*>(S)[((base + row0 + rr) << 6) + l];
        float e0 = fast_exp(sv.x), e1 = fast_exp(sv.y);
        float e2 = fast_exp(sv.z), e3 = fast_exp(sv.w);
        reinterpret_cast<float4*>(ps[rr])[l] = make_float4(e0, e1, e2, e3);
        float s = (e0 + e1) + (e2 + e3);
#pragma unroll
        for (int off = 32; off; off >>= 1) s += __shfl_xor(s, off);
        if (it == 0) rs0 = fast_rcp(s); else rs1 = fast_rcp(s);
    }
    __syncthreads();

    // P @ V: wave w covers k in [64w,64w+64), lane l owns d4=l
    const float4* V4 = reinterpret_cast<const float4*>(V) + base * 64;
    float4 acc[8];
#pragma unroll
    for (int r = 0; r < 8; ++r) acc[r] = make_float4(0.f, 0.f, 0.f, 0.f);

#pragma unroll 2
    for (int k4 = 0; k4 < 16; ++k4) {
        const int m0 = w * 64 + k4 * 4;
        float4 v0 = V4[(m0 + 0) * 64 + l];
        float4 v1 = V4[(m0 + 1) * 64 + l];
        float4 v2 = V4[(m0 + 2) * 64 + l];
        float4 v3 = V4[(m0 + 3) * 64 + l];
#pragma unroll
        for (int r = 0; r < 8; ++r) {
            float4 pr = *reinterpret_cast<const float4*>(&ps[r][m0]);  // uniform b128
            acc[r].x = fmaf(pr.x, v0.x, acc[r].x); acc[r].y = fmaf(pr.x, v0.y, acc[r].y);
            acc[r].z = fmaf(pr.x, v0.z, acc[r].z); acc[r].w = fmaf(pr.x, v0.w, acc[r].w);
            acc[r].x = fmaf(pr.y, v1.x, acc[r].x); acc[r].y = fmaf(pr.y, v1.y, acc[r].y);
            acc[r].z = fmaf(pr.y, v1.z, acc[r].z); acc[r].w = fmaf(pr.y, v1.w, acc[r].w);
            acc[r].x = fmaf(pr.z, v2.x, acc[r].x); acc[r].y = fmaf(pr.z, v2.y, acc[r].y);
            acc[r].z = fmaf(pr.z, v2.z, acc[r].z); acc[r].w = fmaf(pr.z, v2.w, acc[r].w);
            acc[r].x = fmaf(pr.w, v3.x, acc[r].x); acc[r].y = fmaf(pr.w, v3.y, acc[r].y);
            acc[r].z = fmaf(pr.w, v3.z, acc[r].z); acc[r].w = fmaf(pr.w, v3.w, acc[r].w);
        }
    }
#pragma unroll
    for (int r = 0; r < 8; ++r) part[r][w][l] = acc[r];
    __syncthreads();

    // reduce: wave w handles rows {w, w+4}, normalize, store
#pragma unroll
    for (int rr = w, it = 0; rr < 8; rr += 4, ++it) {
        float rs = (it == 0) ? rs0 : rs1;
        float4 q0 = part[rr][0][l], q1 = part[rr][1][l];
        float4 q2 = part[rr][2][l], q3 = part[rr][3][l];
        float4 ov;
        ov.x = ((q0.x + q1.x) + (q2.x + q3.x)) * rs;
        ov.y = ((q0.y + q1.y) + (q2.y + q3.y)) * rs;
        ov.z = ((q0.z + q1.z) + (q2.z + q3.z)) * rs;
        ov.w = ((q0.w + q1.w) + (q2.w + q3.w)) * rs;
        reinterpret_cast<float4*>(o)[((base + row0 + rr) << 6) + l] = ov;
    }
}

extern "C" void kernel_launch(void* const* d_in, const int* in_sizes, int n_in,
                              void* d_out, int out_size, void* d_ws, size_t ws_size,
                              hipStream_t stream)
{
    const float* x    = (const float*)d_in[0];  // [4,256,256]
    const float* mem  = (const float*)d_in[1];  // [4,256,256]
    const int*   mask = (const int*)  d_in[2];  // [4,256]
    const float* w1   = (const float*)d_in[3];  // [256,256]
    const float* b1   = (const float*)d_in[4];  // [256]
    const float* w2   = (const float*)d_in[5];  // [256,256]
    const float* wst  = (const float*)d_in[6];  // [256]

    float* out   = (float*)d_out;               // [4,256,256]
    float* Smask = out + NB * L * L;            // [4,256,256] (masked S, output 1)
    float* agg   = Smask + NB * L * L;          // [4,256,256] (agg_2_h, output 2)

    float* E1R = (float*)d_ws;                  // 1 MiB each
    float* E2R = E1R + NB * L * D;
    float* ST  = E2R + NB * L * D;              // raw S^T

    linear_kernel<<<512, 256, 0, stream>>>(x, mem, w1, b1, w2, E1R, E2R);
    score_kernel<<<512, 256, 0, stream>>>(E1R, E2R, wst, mask, Smask, ST);
    attn_kernel<<<256, 256, 0, stream>>>(x, mem, Smask, ST, out, agg);
}